// Round 1
// baseline (1165.871 us; speedup 1.0000x reference)
//
#include <hip/hip_runtime.h>

// CRF log-likelihood. B=256 batches, L=1024 steps, D=126 emit states, T=128 total.
// One block per batch (256 blocks = 1/CU), 512 threads (8 waves).
// Forward recursion in base-2 log domain; transitions held in registers
// (thread (j=tid>>2, g=tid&3) owns trans[j, g*32 .. g*32+31] * log2e).

#define NEGV    (-10000.0f)
#define LOG2E   1.4426950408889634f
#define LN2     0.6931471805599453f

constexpr int Bc = 256, Lc = 1024, Dc = 126, Tc = 128;

#if __has_builtin(__builtin_amdgcn_exp2f)
#define FEXP2(x) __builtin_amdgcn_exp2f(x)
#else
#define FEXP2(x) exp2f(x)
#endif
#if __has_builtin(__builtin_amdgcn_logf)
#define FLOG2(x) __builtin_amdgcn_logf(x)
#else
#define FLOG2(x) log2f(x)
#endif

__global__ __launch_bounds__(512, 1) void crf_fwd_kernel(
    const float* __restrict__ x,      // [B, L, D]
    const float* __restrict__ trans,  // [T, T] row-major: trans[j*T + k]
    const int*   __restrict__ x_len,  // [B]
    const int*   __restrict__ tag,    // [B, L]
    float*       __restrict__ out)    // [B]
{
    __shared__ __align__(16) float wlds[Tc];    // (alpha - A) * log2e, max == 0
    __shared__ __align__(16) float part[512];   // per-thread exp partial sums
    __shared__ float wavemax[2];
    __shared__ float redsc[2];

    const int b    = blockIdx.x;
    const int tid  = threadIdx.x;
    const int j    = tid >> 2;   // output state this thread contributes to (phase A)
    const int g    = tid & 3;    // k-chunk: k in [g*32, g*32+32)
    const int lane = tid & 63;
    const int wv   = tid >> 6;
    const int len  = x_len[b];   // uniform per block; mask == (l < len)

    const float* xb = x   + (size_t)b * Lc * Dc;
    const int*   tb = tag + (size_t)b * Lc;

    // ---- load transitions chunk into registers, pre-scaled by log2e ----
    float t2r[32];
    {
        const float* tp = trans + j * Tc + g * 32;
#pragma unroll
        for (int c = 0; c < 8; ++c) {
            float4 t4 = reinterpret_cast<const float4*>(tp)[c];
            t2r[4*c+0] = t4.x * LOG2E;
            t2r[4*c+1] = t4.y * LOG2E;
            t2r[4*c+2] = t4.z * LOG2E;
            t2r[4*c+3] = t4.w * LOG2E;
        }
    }

    // ---- init: alpha0 = NEG everywhere except START (=T-2) = 0; base A = 0 ----
    if (tid < Tc) wlds[tid] = (tid == Tc - 2) ? 0.0f : NEGV * LOG2E;
    float Areg    = 0.0f;     // running base (valid on tid < 128)
    float logit_c = NEGV;     // logit for current step (tid < 128; j>=126 stays NEG)
    if (tid < Dc) logit_c = xb[tid];
    __syncthreads();

    // ---- forward recursion ----
    for (int l = 0; l < len; ++l) {
        // prefetch next step's logit (consumed after the barrier)
        float logit_n = NEGV;
        if (tid < Dc) {
            int l2 = (l + 1 < len) ? (l + 1) : l;
            logit_n = xb[(size_t)l2 * Dc + tid];
        }

        // phase A: each thread sums 32 terms 2^(t2 + w)
        {
            const float* wp = wlds + g * 32;
            float s0 = 0.f, s1 = 0.f, s2 = 0.f, s3 = 0.f;
#pragma unroll
            for (int c = 0; c < 8; ++c) {
                float4 w4 = reinterpret_cast<const float4*>(wp)[c];
                s0 += FEXP2(t2r[4*c+0] + w4.x);
                s1 += FEXP2(t2r[4*c+1] + w4.y);
                s2 += FEXP2(t2r[4*c+2] + w4.z);
                s3 += FEXP2(t2r[4*c+3] + w4.w);
            }
            part[tid] = (s0 + s1) + (s2 + s3);
        }
        __syncthreads();

        // phase B1: finish LSE for state jB = tid (tid < 128), wave max
        float v = 0.f;
        if (tid < Tc) {
            float4 p = reinterpret_cast<const float4*>(part)[tid];
            float s  = (p.x + p.y) + (p.z + p.w);
            v = logit_c + LN2 * FLOG2(s);   // alpha_new = Areg + v
            float m = v;
#pragma unroll
            for (int off = 1; off < 64; off <<= 1)
                m = fmaxf(m, __shfl_xor(m, off, 64));
            if (lane == 0) wavemax[wv] = m;
        }
        __syncthreads();

        // phase B2: rebase w so max(w) == 0
        if (tid < Tc) {
            float maxv = fmaxf(wavemax[0], wavemax[1]);
            Areg += maxv;
            wlds[tid] = (v - maxv) * LOG2E;
            logit_c = logit_n;
        }
        __syncthreads();
    }

    // ---- partition = LSE_j(alpha[j] + trans[STOP, j]) ----
    if (tid < Tc) {
        float ts = trans[(Tc - 1) * Tc + tid];
        float p  = FEXP2(wlds[tid] + ts * LOG2E);
#pragma unroll
        for (int off = 1; off < 64; off <<= 1)
            p += __shfl_xor(p, off, 64);
        if (lane == 0) redsc[wv] = p;
    }

    // ---- emission + pairwise transition score (cooperative over l) ----
    float acc = 0.f;
    for (int l = tid; l < len; l += 512) {
        int   tg = tb[l];
        float e  = xb[(size_t)l * Dc + tg];
        float tr = (l == 0) ? trans[tg * Tc + (Tc - 2)]
                            : trans[tg * Tc + tb[l - 1]];
        acc += e + tr;
    }
#pragma unroll
    for (int off = 1; off < 64; off <<= 1)
        acc += __shfl_xor(acc, off, 64);
    __syncthreads();              // part[] reads of last step done; safe to reuse
    if (lane == 0) part[wv] = acc;
    __syncthreads();

    if (tid == 0) {
        float S = redsc[0] + redsc[1];
        float partition = Areg + LN2 * FLOG2(S);
        float tran = trans[(Tc - 1) * Tc + tb[len - 1]];  // STOP transition
#pragma unroll
        for (int w2 = 0; w2 < 8; ++w2) tran += part[w2];
        out[b] = tran - partition;
    }
}

extern "C" void kernel_launch(void* const* d_in, const int* in_sizes, int n_in,
                              void* d_out, int out_size, void* d_ws, size_t ws_size,
                              hipStream_t stream) {
    const float* x     = (const float*)d_in[0];
    const float* trans = (const float*)d_in[1];
    // d_in[2] = x_mask (unused; equivalent to l < x_len)
    const int*   x_len = (const int*)d_in[3];
    const int*   tag   = (const int*)d_in[4];
    float*       out   = (float*)d_out;

    crf_fwd_kernel<<<Bc, 512, 0, stream>>>(x, trans, x_len, tag, out);
}

// Round 2
// 1099.869 us; speedup vs baseline: 1.0600x; 1.0600x over previous
//
#include <hip/hip_runtime.h>

// CRF log-likelihood. B=256, L=1024, D=126, T=128. One block/batch, 512 thr.
// Forward recursion as fp32 matvec in the weight domain:
//   alpha_new[j] = logit[j] + ln2*log2( sum_k T[j,k] * e_k ),
//   T[j,k] = 2^(trans[j,k]*log2e)  (constant, in registers),
//   e_k    = 2^((alpha_k - M)*log2e) (128 floats in LDS, rebased by stale max).
// One barrier per step via double-buffered E/wmax; in-wave shuffle reductions.

#define NEGV    (-10000.0f)
#define LOG2E   1.4426950408889634f
#define LN2     0.6931471805599453f

constexpr int Bc = 256, Lc = 1024, Dc = 126, Tc = 128;

#if __has_builtin(__builtin_amdgcn_exp2f)
#define FEXP2(x) __builtin_amdgcn_exp2f(x)
#else
#define FEXP2(x) exp2f(x)
#endif
#if __has_builtin(__builtin_amdgcn_logf)
#define FLOG2(x) __builtin_amdgcn_logf(x)
#else
#define FLOG2(x) log2f(x)
#endif

__global__ __launch_bounds__(512, 1) void crf_fwd_kernel(
    const float* __restrict__ x,      // [B, L, D]
    const float* __restrict__ trans,  // [T, T] row-major
    const int*   __restrict__ x_len,  // [B]
    const int*   __restrict__ tag,    // [B, L]
    float*       __restrict__ out)    // [B]
{
    __shared__ __align__(16) float E[2][Tc];     // e_k, double-buffered
    __shared__ __align__(16) float wmax[2][8];   // per-wave max of v, dbuf
    __shared__ float red[12];                    // epilogue reductions

    const int b   = blockIdx.x;
    const int tid = threadIdx.x;
    const int w   = tid >> 6;          // wave 0..7  -> owns j in [16w, 16w+16)
    const int l6  = tid & 63;
    const int jj  = l6 & 15;
    const int kq  = l6 >> 4;           // k-quarter 0..3 -> k in [32kq, 32kq+32)
    const int j   = (w << 4) | jj;
    const int k0  = kq << 5;
    const int len = x_len[b];          // block-uniform (mask == l < len)

    const float* xb = x   + (size_t)b * Lc * Dc;
    const int*   tb = tag + (size_t)b * Lc;

    // ---- constant weight row chunk: treg[i] = 2^(trans[j, k0+i] * log2e) ----
    float treg[32];
    {
        const float4* tp = reinterpret_cast<const float4*>(trans + j * Tc + k0);
#pragma unroll
        for (int c = 0; c < 8; ++c) {
            float4 t4 = tp[c];
            treg[4*c+0] = FEXP2(t4.x * LOG2E);
            treg[4*c+1] = FEXP2(t4.y * LOG2E);
            treg[4*c+2] = FEXP2(t4.z * LOG2E);
            treg[4*c+3] = FEXP2(t4.w * LOG2E);
        }
    }

    // ---- init: alpha0 = NEG except START(=126)=0; M=0 → e = 1 at START ----
    float l2cur = (j < Dc) ? xb[j] * LOG2E : NEGV * LOG2E;
    if (tid < Tc)  E[0][tid] = (tid == Tc - 2) ? 1.0f : 0.0f;
    if (tid < 8)   { wmax[0][tid] = 0.0f; wmax[1][tid] = 0.0f; }
    __syncthreads();

    // ---- forward recursion: ONE barrier per step ----
    float M = 0.0f, cprev = 0.0f;   // base-2 shift bookkeeping (uniform)
    for (int l = 0; l < len; ++l) {
        const int p = l & 1;

        // stale global max (written during previous step)
        float4 wm0 = *reinterpret_cast<const float4*>(&wmax[p][0]);
        float4 wm1 = *reinterpret_cast<const float4*>(&wmax[p][4]);
        float cnew = fmaxf(fmaxf(fmaxf(wm0.x, wm0.y), fmaxf(wm0.z, wm0.w)),
                           fmaxf(fmaxf(wm1.x, wm1.y), fmaxf(wm1.z, wm1.w)));
        M += cprev; cprev = cnew;

        // prefetch next logit (global, ~1.5 steps of latency cover)
        float lnxt = NEGV;
        if (j < Dc) { int li = (l + 1 < len) ? (l + 1) : l; lnxt = xb[(size_t)li * Dc + j]; }

        // matvec partial: s = sum over this thread's 32 k's of T[j,k]*e_k
        // bank-stagger by kq so the 4 broadcast groups hit disjoint banks
        float s0 = 0.f, s1 = 0.f, s2 = 0.f, s3 = 0.f;
#pragma unroll
        for (int c = 0; c < 8; ++c) {
            int cc = (c + 2 * kq) & 7;
            float4 e4 = *reinterpret_cast<const float4*>(&E[p][k0 + 4 * cc]);
            s0 = fmaf(treg[4*cc+0], e4.x, s0);
            s1 = fmaf(treg[4*cc+1], e4.y, s1);
            s2 = fmaf(treg[4*cc+2], e4.z, s2);
            s3 = fmaf(treg[4*cc+3], e4.w, s3);
        }
        float s = (s0 + s1) + (s2 + s3);
        s += __shfl_xor(s, 16, 64);     // reduce across kq
        s += __shfl_xor(s, 32, 64);

        float v = l2cur + FLOG2(s);     // v = (alpha_new - M)*log2e

        // wave max over its 16 j's (kq groups hold identical v sets)
        float m = v;
#pragma unroll
        for (int off = 1; off < 16; off <<= 1)
            m = fmaxf(m, __shfl_xor(m, off, 64));

        // write next-step state (rebased by stale max)
        float e = FEXP2(v - cnew);
        if (kq == 0) E[p ^ 1][j] = e;           // 16 consecutive banks, clean
        if (l6 == 0) wmax[p ^ 1][w] = m;

        l2cur = (j < Dc) ? lnxt * LOG2E : NEGV * LOG2E;
        __syncthreads();
    }
    const float Mf = M + cprev;         // final shift: alpha = Mf + log2(E)
    const int   pf = len & 1;

    // ---- score: emission + pairwise transitions (cooperative over l) ----
    float acc = 0.f;
    for (int l = tid; l < len; l += 512) {
        int   tg = tb[l];
        float tr = (l == 0) ? trans[tg * Tc + (Tc - 2)]
                            : trans[tg * Tc + tb[l - 1]];
        acc += xb[(size_t)l * Dc + tg] + tr;
    }
#pragma unroll
    for (int off = 1; off < 64; off <<= 1)
        acc += __shfl_xor(acc, off, 64);
    if (l6 == 0) red[w] = acc;

    // ---- partition = ln2 * (Mf + log2(sum_k 2^(trans[STOP,k]*log2e) * e_k)) ----
    if (w == 0) {
        float p0 = FEXP2(trans[(Tc-1) * Tc + l6]      * LOG2E) * E[pf][l6];
        float p1 = FEXP2(trans[(Tc-1) * Tc + 64 + l6] * LOG2E) * E[pf][64 + l6];
        float ps = p0 + p1;
#pragma unroll
        for (int off = 1; off < 64; off <<= 1)
            ps += __shfl_xor(ps, off, 64);
        if (l6 == 0) red[8] = LN2 * (Mf + FLOG2(ps));
    }
    __syncthreads();

    if (tid == 0) {
        float sc = trans[(Tc-1) * Tc + tb[len - 1]];   // STOP transition
#pragma unroll
        for (int i = 0; i < 8; ++i) sc += red[i];
        out[b] = sc - red[8];
    }
}

extern "C" void kernel_launch(void* const* d_in, const int* in_sizes, int n_in,
                              void* d_out, int out_size, void* d_ws, size_t ws_size,
                              hipStream_t stream) {
    const float* x     = (const float*)d_in[0];
    const float* trans = (const float*)d_in[1];
    // d_in[2] = x_mask (redundant with x_len)
    const int*   x_len = (const int*)d_in[3];
    const int*   tag   = (const int*)d_in[4];
    float*       out   = (float*)d_out;

    crf_fwd_kernel<<<Bc, 512, 0, stream>>>(x, trans, x_len, tag, out);
}

// Round 3
// 868.035 us; speedup vs baseline: 1.3431x; 1.2671x over previous
//
#include <hip/hip_runtime.h>

// CRF log-likelihood. B=256, L=1024, D=126, T=128. One block/batch, 512 thr.
// Forward recursion as a pure fp32 matvec in the probability domain with
// exact power-of-2 rebasing:
//   E_l[k]    = 2^(alpha_l[k]*log2e - M_l)          (128 floats in LDS, dbuf)
//   s_j       = sum_k T[j,k] * E_l[k],  T = 2^(trans*log2e) const in regs
//   E_{l+1}[j]= s_j * P_j * R,  P_j = 2^(logit_j*log2e) (off-chain exp2),
//   R = 2^-(ilogb of subset-max of E_l)  (bit-hack; M_{l+1}=M_l+shift exact).
// No log2/exp2/cross-wave reduction on the serial chain; quad reductions via
// DPP quad_perm; one barrier per step.
// Lane map: kq = tid&3 (k-quarter), jj = (tid>>2)&15, j = 16*(tid>>6) + jj.

#define NEGV    (-10000.0f)
#define LOG2E   1.4426950408889634f
#define LN2     0.6931471805599453f

constexpr int Bc = 256, Lc = 1024, Dc = 126, Tc = 128;

#if __has_builtin(__builtin_amdgcn_exp2f)
#define FEXP2(x) __builtin_amdgcn_exp2f(x)
#else
#define FEXP2(x) exp2f(x)
#endif
#if __has_builtin(__builtin_amdgcn_logf)
#define FLOG2(x) __builtin_amdgcn_logf(x)
#else
#define FLOG2(x) log2f(x)
#endif

// quad_perm DPP: xor1 = {1,0,3,2} -> 0xB1, xor2 = {2,3,0,1} -> 0x4E
#if __has_builtin(__builtin_amdgcn_mov_dpp)
#define QXOR1(x) __int_as_float(__builtin_amdgcn_mov_dpp(__float_as_int(x), 0xB1, 0xF, 0xF, true))
#define QXOR2(x) __int_as_float(__builtin_amdgcn_mov_dpp(__float_as_int(x), 0x4E, 0xF, 0xF, true))
#else
#define QXOR1(x) __shfl_xor((x), 1, 64)
#define QXOR2(x) __shfl_xor((x), 2, 64)
#endif

__global__ __launch_bounds__(512, 1) void crf_fwd_kernel(
    const float* __restrict__ x,      // [B, L, D]
    const float* __restrict__ trans,  // [T, T] row-major
    const int*   __restrict__ x_len,  // [B]
    const int*   __restrict__ tag,    // [B, L]
    float*       __restrict__ out)    // [B]
{
    __shared__ __align__(16) float E[2][Tc];   // rebased exp(alpha), dbuf
    __shared__ float red[12];                  // epilogue reductions

    const int b   = blockIdx.x;
    const int tid = threadIdx.x;
    const int w   = tid >> 6;            // wave 0..7 -> j in [16w, 16w+16)
    const int l6  = tid & 63;
    const int kq  = l6 & 3;              // k-quarter: k in [32kq, 32kq+32)
    const int jj  = l6 >> 2;             // 0..15
    const int j   = (w << 4) | jj;
    const int k0  = kq << 5;
    const int len = x_len[b];            // block-uniform (mask == l < len)

    const float* xb = x   + (size_t)b * Lc * Dc;
    const int*   tb = tag + (size_t)b * Lc;

    // ---- constant weights: treg[i] = 2^(trans[j, k0+i] * log2e) ----
    float treg[32];
    {
        const float4* tp = reinterpret_cast<const float4*>(trans + j * Tc + k0);
#pragma unroll
        for (int c = 0; c < 8; ++c) {
            float4 t4 = tp[c];
            treg[4*c+0] = FEXP2(t4.x * LOG2E);
            treg[4*c+1] = FEXP2(t4.y * LOG2E);
            treg[4*c+2] = FEXP2(t4.z * LOG2E);
            treg[4*c+3] = FEXP2(t4.w * LOG2E);
        }
    }

    // ---- init: alpha0 = NEG except START(=126)=0 -> E = delta(126), M=0 ----
    if (tid < Tc) E[0][tid] = (tid == Tc - 2) ? 1.0f : 0.0f;
    float Pcur = (j < Dc) ? FEXP2(xb[j] * LOG2E) : 0.0f;
    int   Mint = 0;                      // exact base-2 shift accumulator
    __syncthreads();

    // ---- forward recursion: ONE barrier/step, no transcendentals on chain ----
    for (int l = 0; l < len; ++l) {
        const int p = l & 1;

        // off-chain: prefetch next logit (global; consumed ~250 cyc later)
        float lnxt = 0.0f;
        if (j < Dc) { int li = (l + 1 < len) ? (l + 1) : l; lnxt = xb[(size_t)li * Dc + j]; }

        // matvec partials + subset max of input E (k = 2 mod 4 incl. START)
        const float* Ep = &E[p][k0];
        float s0 = 0.f, s1 = 0.f, s2 = 0.f, s3 = 0.f, mx = 0.f;
#pragma unroll
        for (int c = 0; c < 8; ++c) {
            int cc = (c + 2 * kq) & 7;   // bank-stagger across the quad
            float4 e4 = *reinterpret_cast<const float4*>(Ep + 4 * cc);
            s0 = fmaf(treg[4*cc+0], e4.x, s0);
            s1 = fmaf(treg[4*cc+1], e4.y, s1);
            s2 = fmaf(treg[4*cc+2], e4.z, s2);
            s3 = fmaf(treg[4*cc+3], e4.w, s3);
            mx = fmaxf(mx, e4.z);
        }
        float s = (s0 + s1) + (s2 + s3);
        s += QXOR1(s);                   // quad reduce across kq (DPP, ~4 cyc)
        s += QXOR2(s);
        mx = fmaxf(mx, QXOR1(mx));
        mx = fmaxf(mx, QXOR2(mx));

        // rebase scale R = 2^(127-eb); exact shift bookkeeping in integers
        int   eb = (__float_as_int(mx) >> 23) & 0xFF;
        float R  = __int_as_float((254 - eb) << 23);
        Mint += eb - 127;

        float eout = s * Pcur * R;
        if (kq == 0) E[p ^ 1][j] = eout; // 16 consecutive banks per wave

        Pcur = (j < Dc) ? FEXP2(lnxt * LOG2E) : 0.0f;   // off-chain exp2
        __syncthreads();
    }
    const int pf = len & 1;              // final E buffer

    // ---- score: emission + pairwise transitions (cooperative over l) ----
    float acc = 0.f;
    for (int l = tid; l < len; l += 512) {
        int   tg = tb[l];
        float tr = (l == 0) ? trans[tg * Tc + (Tc - 2)]
                            : trans[tg * Tc + tb[l - 1]];
        acc += xb[(size_t)l * Dc + tg] + tr;
    }
#pragma unroll
    for (int off = 1; off < 64; off <<= 1)
        acc += __shfl_xor(acc, off, 64);
    if (l6 == 0) red[w] = acc;

    // ---- partition = ln2 * (Mint + log2(sum_k 2^(t_stop_k*log2e) * E_k)) ----
    if (w == 0) {
        float p0 = FEXP2(trans[(Tc-1) * Tc + l6]      * LOG2E) * E[pf][l6];
        float p1 = FEXP2(trans[(Tc-1) * Tc + 64 + l6] * LOG2E) * E[pf][64 + l6];
        float ps = p0 + p1;
#pragma unroll
        for (int off = 1; off < 64; off <<= 1)
            ps += __shfl_xor(ps, off, 64);
        if (l6 == 0) red[8] = LN2 * ((float)Mint + FLOG2(ps));
    }
    __syncthreads();

    if (tid == 0) {
        float sc = trans[(Tc-1) * Tc + tb[len - 1]];   // STOP transition
#pragma unroll
        for (int i = 0; i < 8; ++i) sc += red[i];
        out[b] = sc - red[8];
    }
}

extern "C" void kernel_launch(void* const* d_in, const int* in_sizes, int n_in,
                              void* d_out, int out_size, void* d_ws, size_t ws_size,
                              hipStream_t stream) {
    const float* x     = (const float*)d_in[0];
    const float* trans = (const float*)d_in[1];
    // d_in[2] = x_mask (redundant with x_len)
    const int*   x_len = (const int*)d_in[3];
    const int*   tag   = (const int*)d_in[4];
    float*       out   = (float*)d_out;

    crf_fwd_kernel<<<Bc, 512, 0, stream>>>(x, trans, x_len, tag, out);
}

// Round 4
// 607.481 us; speedup vs baseline: 1.9192x; 1.4289x over previous
//
#include <hip/hip_runtime.h>

// CRF log-likelihood. B=256, L=1024, D=126, T=128. One block/batch, 512 thr.
// Forward recursion as fp32 matvec in probability domain (see R3), now with
// logits staged global->LDS 16 steps ahead so HBM/LLC latency is off the
// per-step serial chain:
//   chunk c = steps [16c,16c+16) = 2016 floats; loaded (coalesced float4)
//   at chunk-step 0 into regs, ds_written at chunk-step 8, consumed >=8
//   steps later. One barrier per step; no transcendentals on the chain.

#define NEGV    (-10000.0f)
#define LOG2E   1.4426950408889634f
#define LN2     0.6931471805599453f

constexpr int Bc = 256, Lc = 1024, Dc = 126, Tc = 128;
constexpr int CH = 16, CHF = CH * Dc;       // 2016 floats per chunk
constexpr int NCH = Lc / CH;                // 64 chunks

#if __has_builtin(__builtin_amdgcn_exp2f)
#define FEXP2(x) __builtin_amdgcn_exp2f(x)
#else
#define FEXP2(x) exp2f(x)
#endif
#if __has_builtin(__builtin_amdgcn_logf)
#define FLOG2(x) __builtin_amdgcn_logf(x)
#else
#define FLOG2(x) log2f(x)
#endif

// quad_perm DPP: xor1 = {1,0,3,2} -> 0xB1, xor2 = {2,3,0,1} -> 0x4E
#if __has_builtin(__builtin_amdgcn_mov_dpp)
#define QXOR1(x) __int_as_float(__builtin_amdgcn_mov_dpp(__float_as_int(x), 0xB1, 0xF, 0xF, true))
#define QXOR2(x) __int_as_float(__builtin_amdgcn_mov_dpp(__float_as_int(x), 0x4E, 0xF, 0xF, true))
#else
#define QXOR1(x) __shfl_xor((x), 1, 64)
#define QXOR2(x) __shfl_xor((x), 2, 64)
#endif

__global__ __launch_bounds__(512, 1) void crf_fwd_kernel(
    const float* __restrict__ x,      // [B, L, D]
    const float* __restrict__ trans,  // [T, T] row-major
    const int*   __restrict__ x_len,  // [B]
    const int*   __restrict__ tag,    // [B, L]
    float*       __restrict__ out)    // [B]
{
    __shared__ __align__(16) float E[2][Tc];       // rebased exp(alpha), dbuf
    __shared__ __align__(16) float Lbuf[2][CHF];   // staged logits, dbuf
    __shared__ float red[12];                      // epilogue reductions

    const int b   = blockIdx.x;
    const int tid = threadIdx.x;
    const int w   = tid >> 6;            // wave 0..7 -> j in [16w, 16w+16)
    const int l6  = tid & 63;
    const int kq  = l6 & 3;              // k-quarter: k in [32kq, 32kq+32)
    const int jj  = l6 >> 2;             // 0..15
    const int j   = (w << 4) | jj;
    const int k0  = kq << 5;
    const int len = x_len[b];            // block-uniform (mask == l < len)

    const float* xb = x   + (size_t)b * Lc * Dc;
    const int*   tb = tag + (size_t)b * Lc;

    // ---- constant weights: treg[i] = 2^(trans[j, k0+i] * log2e) ----
    float treg[32];
    {
        const float4* tp = reinterpret_cast<const float4*>(trans + j * Tc + k0);
#pragma unroll
        for (int c = 0; c < 8; ++c) {
            float4 t4 = tp[c];
            treg[4*c+0] = FEXP2(t4.x * LOG2E);
            treg[4*c+1] = FEXP2(t4.y * LOG2E);
            treg[4*c+2] = FEXP2(t4.z * LOG2E);
            treg[4*c+3] = FEXP2(t4.w * LOG2E);
        }
    }

    // ---- preload chunk 0; init E = delta(START=126), M = 0 ----
    {
        float4 q0 = make_float4(0.f, 0.f, 0.f, 0.f);
        if (tid < CHF / 4) q0 = *reinterpret_cast<const float4*>(xb + 4 * tid);
        if (tid < Tc) E[0][tid] = (tid == Tc - 2) ? 1.0f : 0.0f;
        if (tid < CHF / 4) *reinterpret_cast<float4*>(&Lbuf[0][4 * tid]) = q0;
    }
    __syncthreads();

    float Pcur = (j < Dc) ? FEXP2(Lbuf[0][j] * LOG2E) : 0.0f;  // step-0 logit
    int    Mint = 0;                      // exact base-2 shift accumulator
    float4 stq  = make_float4(0.f, 0.f, 0.f, 0.f);             // staging regs

    // ---- forward recursion: ONE barrier/step; logits come from LDS ----
    for (int l = 0; l < len; ++l) {
        const int p   = l & 1;
        const int sub = l & (CH - 1);
        const int cb  = (l >> 4) & 1;

        // staging (block-uniform branches): issue loads at sub==0 for chunk
        // c+1; ds_write them at sub==8 (>= ~8 steps of latency cover)
        if (sub == 0) {
            const int c1 = (l >> 4) + 1;
            if (c1 < NCH && tid < CHF / 4)
                stq = *reinterpret_cast<const float4*>(xb + (size_t)c1 * CHF + 4 * tid);
        } else if (sub == 8) {
            const int c1 = (l >> 4) + 1;
            if (c1 < NCH && tid < CHF / 4)
                *reinterpret_cast<float4*>(&Lbuf[cb ^ 1][4 * tid]) = stq;
        }

        // matvec partials + subset max of input E (k = 2 mod 4, incl. START)
        const float* Ep = &E[p][k0];
        float s0 = 0.f, s1 = 0.f, s2 = 0.f, s3 = 0.f, mx = 0.f;
#pragma unroll
        for (int c = 0; c < 8; ++c) {
            int cc = (c + 2 * kq) & 7;   // bank-stagger across the quad
            float4 e4 = *reinterpret_cast<const float4*>(Ep + 4 * cc);
            s0 = fmaf(treg[4*cc+0], e4.x, s0);
            s1 = fmaf(treg[4*cc+1], e4.y, s1);
            s2 = fmaf(treg[4*cc+2], e4.z, s2);
            s3 = fmaf(treg[4*cc+3], e4.w, s3);
            mx = fmaxf(mx, e4.z);
        }
        float s = (s0 + s1) + (s2 + s3);
        s += QXOR1(s);                   // quad reduce across kq (DPP)
        s += QXOR2(s);
        mx = fmaxf(mx, QXOR1(mx));
        mx = fmaxf(mx, QXOR2(mx));       // identical across all 512 threads

        // rebase scale R = 2^(127-eb); exact shift bookkeeping in integers
        int   eb = (__float_as_int(mx) >> 23) & 0xFF;
        float R  = __int_as_float((254 - eb) << 23);
        Mint += eb - 127;

        float eout = s * Pcur * R;
        if (kq == 0) E[p ^ 1][j] = eout;

        // next-step logit from LDS (off-chain) + exp2
        {
            int   ln = (l + 1 < len) ? (l + 1) : l;
            float lv = (j < Dc) ? Lbuf[(ln >> 4) & 1][(ln & (CH - 1)) * Dc + j] : 0.0f;
            Pcur = (j < Dc) ? FEXP2(lv * LOG2E) : 0.0f;
        }
        __syncthreads();
    }
    const int pf = len & 1;              // final E buffer

    // ---- score: emission + pairwise transitions (cooperative over l) ----
    float acc = 0.f;
    for (int l = tid; l < len; l += 512) {
        int   tg = tb[l];
        float tr = (l == 0) ? trans[tg * Tc + (Tc - 2)]
                            : trans[tg * Tc + tb[l - 1]];
        acc += xb[(size_t)l * Dc + tg] + tr;
    }
#pragma unroll
    for (int off = 1; off < 64; off <<= 1)
        acc += __shfl_xor(acc, off, 64);
    if (l6 == 0) red[w] = acc;

    // ---- partition = ln2 * (Mint + log2(sum_k 2^(t_stop_k*log2e) * E_k)) ----
    if (w == 0) {
        float p0 = FEXP2(trans[(Tc-1) * Tc + l6]      * LOG2E) * E[pf][l6];
        float p1 = FEXP2(trans[(Tc-1) * Tc + 64 + l6] * LOG2E) * E[pf][64 + l6];
        float ps = p0 + p1;
#pragma unroll
        for (int off = 1; off < 64; off <<= 1)
            ps += __shfl_xor(ps, off, 64);
        if (l6 == 0) red[8] = LN2 * ((float)Mint + FLOG2(ps));
    }
    __syncthreads();

    if (tid == 0) {
        float sc = trans[(Tc-1) * Tc + tb[len - 1]];   // STOP transition
#pragma unroll
        for (int i = 0; i < 8; ++i) sc += red[i];
        out[b] = sc - red[8];
    }
}

extern "C" void kernel_launch(void* const* d_in, const int* in_sizes, int n_in,
                              void* d_out, int out_size, void* d_ws, size_t ws_size,
                              hipStream_t stream) {
    const float* x     = (const float*)d_in[0];
    const float* trans = (const float*)d_in[1];
    // d_in[2] = x_mask (redundant with x_len)
    const int*   x_len = (const int*)d_in[3];
    const int*   tag   = (const int*)d_in[4];
    float*       out   = (float*)d_out;

    crf_fwd_kernel<<<Bc, 512, 0, stream>>>(x, trans, x_len, tag, out);
}